// Round 6
// baseline (451.403 us; speedup 1.0000x reference)
//
#include <hip/hip_runtime.h>

// Problem constants (from reference):
//   B=1024, HIS=50, K=5, D=256, SIG=100, N=HIS*K=250
#define HIS_ 50
#define KK   5
#define DD   256
#define SIG_ 100
#define NN   250   // HIS_*KK

typedef float f4 __attribute__((ext_vector_type(4)));

// Block-wide (256 threads = 4 waves) exclusive prefix sum of `v`.
// Also returns the block total via *total. Uses wsum[4] in LDS; contains
// two __syncthreads (the trailing one protects wsum for back-to-back calls).
__device__ __forceinline__ int block_scan_excl(int v, int tid,
                                               volatile int* wsum, int* total)
{
    const int lane = tid & 63;
    const int wave = tid >> 6;
    int x = v;
    #pragma unroll
    for (int d = 1; d < 64; d <<= 1) {
        const int u = __shfl_up(x, d, 64);
        if (lane >= d) x += u;
    }
    if (lane == 63) wsum[wave] = x;   // wave-inclusive total
    __syncthreads();
    const int w0 = wsum[0], w1 = wsum[1], w2 = wsum[2], w3 = wsum[3];
    *total = w0 + w1 + w2 + w3;
    int base = 0;
    if (wave > 0) base += w0;
    if (wave > 1) base += w1;
    if (wave > 2) base += w2;
    __syncthreads();                   // allow wsum reuse by a later scan
    return base + x - v;               // exclusive prefix
}

// One block per batch element. 256 threads = 4 waves.
// Phase A (fully parallel): dedup 250 vocab ids -> CSR segments in LDS.
// Phase B: stream term rows -> output, each row read once, written once.
// id_st / news_st: element stride for the integer inputs (1 = int32 as the
// harness documents; 2 = low word of little-endian int64, defensive).
__global__ __launch_bounds__(256, 4) void fuse_dedup_kernel(
    const float* __restrict__ ps_terms,    // [B, N, D] fp32
    const int*   __restrict__ ps_term_ids, // [B, N]   (values in [0,SIG))
    const int*   __restrict__ his_news,    // [B, HIS, SIG]
    float* __restrict__ out,               // [B, N, D] fp32
    const int id_st, const int news_st)
{
    __shared__ __align__(16) int ids[NN + 2]; // vocab ids (+2 pad for int4)
    __shared__ int cnt[NN];      // contributors per segment (by rank)
    __shared__ int off[NN];      // CSR start offset per segment
    __shared__ int lst[NN];      // CSR contributor list (position indices)
    __shared__ int segof[NN];    // dense rank at first-occurrence positions
    __shared__ int wsum[4];      // scan scratch

    const int b   = blockIdx.x;
    const int tid = threadIdx.x;

    // ---- A1: gather vocab ids; zero counts; pad ids ----
    if (tid < NN) {
        const int h   = tid / KK;
        const int pid = ps_term_ids[(size_t)(b * NN + tid) * id_st]; // [0,SIG)
        ids[tid] = his_news[(size_t)((b * HIS_ + h) * SIG_ + pid) * news_st];
        cnt[tid] = 0;
    }
    if (tid >= NN && tid < NN + 2) ids[tid] = -1;             // never matches
    __syncthreads();

    // ---- A2: per-position first-match index f, earlier-match count o,
    //          total-match count tot. int4 LDS reads (wave-uniform => bcast).
    const int myid = (tid < NN) ? ids[tid] : (-2 - tid);      // unique sentinel
    int f = NN, o = 0, tot = 0;
    #pragma unroll 4
    for (int j4 = 0; j4 < (NN + 2) / 4; ++j4) {               // 63 iters
        const int4 q  = *reinterpret_cast<const int4*>(&ids[j4 * 4]);
        const int  jb = j4 * 4;
        { const bool m = (q.x == myid); tot += m; o += (m & (jb + 0 < tid)); if (m && jb + 0 < f) f = jb + 0; }
        { const bool m = (q.y == myid); tot += m; o += (m & (jb + 1 < tid)); if (m && jb + 1 < f) f = jb + 1; }
        { const bool m = (q.z == myid); tot += m; o += (m & (jb + 2 < tid)); if (m && jb + 2 < f) f = jb + 2; }
        { const bool m = (q.w == myid); tot += m; o += (m & (jb + 3 < tid)); if (m && jb + 3 < f) f = jb + 3; }
    }

    // ---- A3 (parallel): dense rank of firsts via exclusive scan ----
    const int flag = (tid < NN && f == tid) ? 1 : 0;
    int nu;                                                   // #unique segs
    const int rank = block_scan_excl(flag, tid, wsum, &nu);
    if (flag) { segof[tid] = rank; cnt[rank] = tot; }
    __syncthreads();
    const int s = (tid < NN) ? segof[f] : 0;                  // my segment id

    // CSR offsets: exclusive scan of per-segment counts
    const int c = (tid < NN) ? cnt[tid] : 0;
    int dummy;
    const int myoff = block_scan_excl(c, tid, wsum, &dummy);
    if (tid < NN) off[tid] = myoff;
    __syncthreads();

    // ---- A4: scatter CSR list, position-ascending within each segment ----
    if (tid < NN) lst[off[s] + o] = tid;
    __syncthreads();

    // ---- Phase B: one wave per row, 4 rows/iter; lane owns a float4 ----
    const int wv   = tid >> 6;
    const int lane = tid & 63;
    const float* bp = ps_terms + (size_t)b * NN * DD;
    float*       op = out      + (size_t)b * NN * DD;
    const f4 zero = {0.f, 0.f, 0.f, 0.f};

    for (int r0 = wv; r0 < NN; r0 += 16) {
        const int ra = r0, rb = r0 + 4, rc = r0 + 8, rd = r0 + 12;
        const int cc0 = (ra < nu) ? cnt[ra] : 0;  const int oo0 = (cc0 > 0) ? off[ra] : 0;
        const int cc1 = (rb < nu) ? cnt[rb] : 0;  const int oo1 = (cc1 > 0) ? off[rb] : 0;
        const int cc2 = (rc < nu) ? cnt[rc] : 0;  const int oo2 = (cc2 > 0) ? off[rc] : 0;
        const int cc3 = (rd < nu) ? cnt[rd] : 0;  const int oo3 = (cc3 > 0) ? off[rd] : 0;
        const int j0 = (cc0 > 0) ? lst[oo0] : 0;
        const int j1 = (cc1 > 0) ? lst[oo1] : 0;
        const int j2 = (cc2 > 0) ? lst[oo2] : 0;
        const int j3 = (cc3 > 0) ? lst[oo3] : 0;
        // Unconditional loads (safe addrs): all 4 in flight before any use.
        const f4 v0 = __builtin_nontemporal_load(
            reinterpret_cast<const f4*>(bp + (size_t)j0 * DD + lane * 4));
        const f4 v1 = __builtin_nontemporal_load(
            reinterpret_cast<const f4*>(bp + (size_t)j1 * DD + lane * 4));
        const f4 v2 = __builtin_nontemporal_load(
            reinterpret_cast<const f4*>(bp + (size_t)j2 * DD + lane * 4));
        const f4 v3 = __builtin_nontemporal_load(
            reinterpret_cast<const f4*>(bp + (size_t)j3 * DD + lane * 4));
        f4 a0 = (cc0 > 0) ? v0 : zero;
        f4 a1 = (cc1 > 0) ? v1 : zero;
        f4 a2 = (cc2 > 0) ? v2 : zero;
        f4 a3 = (cc3 > 0) ? v3 : zero;
        // Rare: extra contributors (duplicate vocab ids), position-ascending.
        for (int t = 1; t < cc0; ++t)
            a0 += __builtin_nontemporal_load(reinterpret_cast<const f4*>(
                bp + (size_t)lst[oo0 + t] * DD + lane * 4));
        for (int t = 1; t < cc1; ++t)
            a1 += __builtin_nontemporal_load(reinterpret_cast<const f4*>(
                bp + (size_t)lst[oo1 + t] * DD + lane * 4));
        for (int t = 1; t < cc2; ++t)
            a2 += __builtin_nontemporal_load(reinterpret_cast<const f4*>(
                bp + (size_t)lst[oo2 + t] * DD + lane * 4));
        for (int t = 1; t < cc3; ++t)
            a3 += __builtin_nontemporal_load(reinterpret_cast<const f4*>(
                bp + (size_t)lst[oo3 + t] * DD + lane * 4));
        __builtin_nontemporal_store(a0,
            reinterpret_cast<f4*>(op + (size_t)ra * DD + lane * 4));
        if (rb < NN) __builtin_nontemporal_store(a1,
            reinterpret_cast<f4*>(op + (size_t)rb * DD + lane * 4));
        if (rc < NN) __builtin_nontemporal_store(a2,
            reinterpret_cast<f4*>(op + (size_t)rc * DD + lane * 4));
        if (rd < NN) __builtin_nontemporal_store(a3,
            reinterpret_cast<f4*>(op + (size_t)rd * DD + lane * 4));
    }
}

extern "C" void kernel_launch(void* const* d_in, const int* in_sizes, int n_in,
                              void* d_out, int out_size, void* d_ws, size_t ws_size,
                              hipStream_t stream) {
    const float* ps_terms    = (const float*)d_in[0];  // [B, HIS, K, D] fp32
    const int*   ps_term_ids = (const int*)d_in[1];    // [B, HIS, K]
    const int*   his_news    = (const int*)d_in[2];    // [B, HIS, SIG]
    float* out = (float*)d_out;                        // [B, HIS*K, D] fp32

    const int Bn = in_sizes[0] / (HIS_ * KK * DD);     // batch from fp32 input

    // Defensive: if the harness ever reports int64 element counts as 32-bit
    // words, in_sizes would be 2x the logical count; read the low words.
    const int id_st   = (in_sizes[1] == 2 * Bn * NN) ? 2 : 1;
    const int news_st = (in_sizes[2] == 2 * Bn * HIS_ * SIG_) ? 2 : 1;

    fuse_dedup_kernel<<<dim3(Bn), dim3(256), 0, stream>>>(
        ps_terms, ps_term_ids, his_news, out, id_st, news_st);
}

// Round 10
// 443.923 us; speedup vs baseline: 1.0168x; 1.0168x over previous
//
#include <hip/hip_runtime.h>

// Problem constants (from reference):
//   B=1024, HIS=50, K=5, D=256, SIG=100, N=HIS*K=250
#define HIS_ 50
#define KK   5
#define DD   256
#define SIG_ 100
#define NN   250   // HIS_*KK

typedef float f4 __attribute__((ext_vector_type(4)));

// Block-wide (256 threads = 4 waves) exclusive prefix sum of `v`.
// Also returns the block total via *total. Uses wsum[4] in LDS; contains
// two __syncthreads (the trailing one protects wsum for back-to-back calls).
__device__ __forceinline__ int block_scan_excl(int v, int tid,
                                               volatile int* wsum, int* total)
{
    const int lane = tid & 63;
    const int wave = tid >> 6;
    int x = v;
    #pragma unroll
    for (int d = 1; d < 64; d <<= 1) {
        const int u = __shfl_up(x, d, 64);
        if (lane >= d) x += u;
    }
    if (lane == 63) wsum[wave] = x;   // wave-inclusive total
    __syncthreads();
    const int w0 = wsum[0], w1 = wsum[1], w2 = wsum[2], w3 = wsum[3];
    *total = w0 + w1 + w2 + w3;
    int base = 0;
    if (wave > 0) base += w0;
    if (wave > 1) base += w1;
    if (wave > 2) base += w2;
    __syncthreads();                   // allow wsum reuse by a later scan
    return base + x - v;               // exclusive prefix
}

// TWO blocks per batch element (grid = 2*B). Both halves run Phase A
// (cheap, ~2us, redundant) so no cross-block sync is needed; Phase B rows
// are interleaved 8-ways across the two blocks' 4 waves each. With
// __launch_bounds__(256,4) only half the grid is co-resident, so later
// blocks' Phase A overlaps earlier blocks' Phase B streaming.
__global__ __launch_bounds__(256, 4) void fuse_dedup_kernel(
    const float* __restrict__ ps_terms,    // [B, N, D] fp32
    const int*   __restrict__ ps_term_ids, // [B, N]   (values in [0,SIG))
    const int*   __restrict__ his_news,    // [B, HIS, SIG]
    float* __restrict__ out,               // [B, N, D] fp32
    const int id_st, const int news_st)
{
    __shared__ __align__(16) int ids[NN + 2]; // vocab ids (+2 pad for int4)
    __shared__ int cnt[NN];      // contributors per segment (by rank)
    __shared__ int off[NN];      // CSR start offset per segment
    __shared__ int lst[NN];      // CSR contributor list (position indices)
    __shared__ int segof[NN];    // dense rank at first-occurrence positions
    __shared__ int wsum[4];      // scan scratch

    const int b    = blockIdx.x >> 1;
    const int half = blockIdx.x & 1;
    const int tid  = threadIdx.x;

    // ---- A1: gather vocab ids; zero counts; pad ids ----
    if (tid < NN) {
        const int h   = tid / KK;
        const int pid = ps_term_ids[(size_t)(b * NN + tid) * id_st]; // [0,SIG)
        ids[tid] = his_news[(size_t)((b * HIS_ + h) * SIG_ + pid) * news_st];
        cnt[tid] = 0;
    }
    if (tid >= NN && tid < NN + 2) ids[tid] = -1;             // never matches
    __syncthreads();

    // ---- A2: per-position first-match index f, earlier-match count o,
    //          total-match count tot. int4 LDS reads (wave-uniform => bcast).
    const int myid = (tid < NN) ? ids[tid] : (-2 - tid);      // unique sentinel
    int f = NN, o = 0, tot = 0;
    #pragma unroll 4
    for (int j4 = 0; j4 < (NN + 2) / 4; ++j4) {               // 63 iters
        const int4 q  = *reinterpret_cast<const int4*>(&ids[j4 * 4]);
        const int  jb = j4 * 4;
        { const bool m = (q.x == myid); tot += m; o += (m & (jb + 0 < tid)); if (m && jb + 0 < f) f = jb + 0; }
        { const bool m = (q.y == myid); tot += m; o += (m & (jb + 1 < tid)); if (m && jb + 1 < f) f = jb + 1; }
        { const bool m = (q.z == myid); tot += m; o += (m & (jb + 2 < tid)); if (m && jb + 2 < f) f = jb + 2; }
        { const bool m = (q.w == myid); tot += m; o += (m & (jb + 3 < tid)); if (m && jb + 3 < f) f = jb + 3; }
    }

    // ---- A3 (parallel): dense rank of firsts via exclusive scan ----
    const int flag = (tid < NN && f == tid) ? 1 : 0;
    int nu;                                                   // #unique segs
    const int rank = block_scan_excl(flag, tid, wsum, &nu);
    if (flag) { segof[tid] = rank; cnt[rank] = tot; }
    __syncthreads();
    const int s = (tid < NN) ? segof[f] : 0;                  // my segment id

    // CSR offsets: exclusive scan of per-segment counts
    const int c = (tid < NN) ? cnt[tid] : 0;
    int dummy;
    const int myoff = block_scan_excl(c, tid, wsum, &dummy);
    if (tid < NN) off[tid] = myoff;
    __syncthreads();

    // ---- A4: scatter CSR list, position-ascending within each segment ----
    if (tid < NN) lst[off[s] + o] = tid;
    __syncthreads();

    // ---- Phase B: 8 logical waves (2 blocks x 4 waves), 4 rows/iter ----
    const int wv   = tid >> 6;
    const int wg   = (half << 2) + wv;      // global wave id in [0,8)
    const int lane = tid & 63;
    const float* bp = ps_terms + (size_t)b * NN * DD;
    float*       op = out      + (size_t)b * NN * DD;
    const f4 zero = {0.f, 0.f, 0.f, 0.f};

    for (int r0 = wg; r0 < NN; r0 += 32) {
        const int ra = r0, rb = r0 + 8, rc = r0 + 16, rd = r0 + 24;
        const int cc0 = (ra < nu) ? cnt[ra] : 0;  const int oo0 = (cc0 > 0) ? off[ra] : 0;
        const int cc1 = (rb < NN && rb < nu) ? cnt[rb] : 0;  const int oo1 = (cc1 > 0) ? off[rb] : 0;
        const int cc2 = (rc < NN && rc < nu) ? cnt[rc] : 0;  const int oo2 = (cc2 > 0) ? off[rc] : 0;
        const int cc3 = (rd < NN && rd < nu) ? cnt[rd] : 0;  const int oo3 = (cc3 > 0) ? off[rd] : 0;
        const int j0 = (cc0 > 0) ? lst[oo0] : 0;
        const int j1 = (cc1 > 0) ? lst[oo1] : 0;
        const int j2 = (cc2 > 0) ? lst[oo2] : 0;
        const int j3 = (cc3 > 0) ? lst[oo3] : 0;
        // Unconditional loads (safe addrs): all 4 in flight before any use.
        const f4 v0 = __builtin_nontemporal_load(
            reinterpret_cast<const f4*>(bp + (size_t)j0 * DD + lane * 4));
        const f4 v1 = __builtin_nontemporal_load(
            reinterpret_cast<const f4*>(bp + (size_t)j1 * DD + lane * 4));
        const f4 v2 = __builtin_nontemporal_load(
            reinterpret_cast<const f4*>(bp + (size_t)j2 * DD + lane * 4));
        const f4 v3 = __builtin_nontemporal_load(
            reinterpret_cast<const f4*>(bp + (size_t)j3 * DD + lane * 4));
        f4 a0 = (cc0 > 0) ? v0 : zero;
        f4 a1 = (cc1 > 0) ? v1 : zero;
        f4 a2 = (cc2 > 0) ? v2 : zero;
        f4 a3 = (cc3 > 0) ? v3 : zero;
        // Rare: extra contributors (duplicate vocab ids), position-ascending.
        for (int t = 1; t < cc0; ++t)
            a0 += __builtin_nontemporal_load(reinterpret_cast<const f4*>(
                bp + (size_t)lst[oo0 + t] * DD + lane * 4));
        for (int t = 1; t < cc1; ++t)
            a1 += __builtin_nontemporal_load(reinterpret_cast<const f4*>(
                bp + (size_t)lst[oo1 + t] * DD + lane * 4));
        for (int t = 1; t < cc2; ++t)
            a2 += __builtin_nontemporal_load(reinterpret_cast<const f4*>(
                bp + (size_t)lst[oo2 + t] * DD + lane * 4));
        for (int t = 1; t < cc3; ++t)
            a3 += __builtin_nontemporal_load(reinterpret_cast<const f4*>(
                bp + (size_t)lst[oo3 + t] * DD + lane * 4));
        __builtin_nontemporal_store(a0,
            reinterpret_cast<f4*>(op + (size_t)ra * DD + lane * 4));
        if (rb < NN) __builtin_nontemporal_store(a1,
            reinterpret_cast<f4*>(op + (size_t)rb * DD + lane * 4));
        if (rc < NN) __builtin_nontemporal_store(a2,
            reinterpret_cast<f4*>(op + (size_t)rc * DD + lane * 4));
        if (rd < NN) __builtin_nontemporal_store(a3,
            reinterpret_cast<f4*>(op + (size_t)rd * DD + lane * 4));
    }
}

extern "C" void kernel_launch(void* const* d_in, const int* in_sizes, int n_in,
                              void* d_out, int out_size, void* d_ws, size_t ws_size,
                              hipStream_t stream) {
    const float* ps_terms    = (const float*)d_in[0];  // [B, HIS, K, D] fp32
    const int*   ps_term_ids = (const int*)d_in[1];    // [B, HIS, K]
    const int*   his_news    = (const int*)d_in[2];    // [B, HIS, SIG]
    float* out = (float*)d_out;                        // [B, HIS*K, D] fp32

    const int Bn = in_sizes[0] / (HIS_ * KK * DD);     // batch from fp32 input

    // Defensive: if the harness ever reports int64 element counts as 32-bit
    // words, in_sizes would be 2x the logical count; read the low words.
    const int id_st   = (in_sizes[1] == 2 * Bn * NN) ? 2 : 1;
    const int news_st = (in_sizes[2] == 2 * Bn * HIS_ * SIG_) ? 2 : 1;

    fuse_dedup_kernel<<<dim3(Bn * 2), dim3(256), 0, stream>>>(
        ps_terms, ps_term_ids, his_news, out, id_st, news_st);
}